// Round 1
// baseline (104.998 us; speedup 1.0000x reference)
//
#include <hip/hip_runtime.h>
#include <hip/hip_bf16.h>

typedef __attribute__((ext_vector_type(8))) short bf16x8;
typedef __attribute__((ext_vector_type(4))) float f32x4;

// ---------------------------------------------------------------------------
// Kernel 1: normalize weight rows (exact fp32), write bf16, K reordered to
// (kh*3+kw)*64 + c so that c (64 wide) is the contiguous MFMA-K inner dim.
// ---------------------------------------------------------------------------
__global__ void wnorm_kernel(const float* __restrict__ w,
                             ushort* __restrict__ wt) {
  const int o = blockIdx.x;    // 0..255
  const int c = threadIdx.x;   // 0..63
  float v[9];
  float ss = 0.f;
  const float* row = w + o * 576 + c * 9;
#pragma unroll
  for (int j = 0; j < 9; ++j) { v[j] = row[j]; ss += v[j] * v[j]; }
#pragma unroll
  for (int off = 32; off > 0; off >>= 1) ss += __shfl_xor(ss, off);
  const float nrm = fmaxf(sqrtf(ss), 1e-12f);
  const float inv = 1.0f / nrm;
#pragma unroll
  for (int j = 0; j < 9; ++j) {
    __hip_bfloat16 h = __float2bfloat16(v[j] * inv);
    wt[o * 576 + j * 64 + c] = *reinterpret_cast<ushort*>(&h);
  }
}

// ---------------------------------------------------------------------------
// Main kernel: one block per (image b, output row-pair y0).
// Computes dots via bf16 MFMA GEMM (M=128 positions x N=256 outputs x K=576),
// patch norms in fp32, exp epilogue, 2x2 avg pool, writes [B][O][32][32].
//
// LDS layout (bytes):
//   [    0, 33792) xs   : bf16 x-tile [4 rows][66 cols][64 c], 16B-block XOR
//                         swizzle: byte ^= (col&7)<<4  (bank-conflict-free)
//   [33792, 34304) invp : float[128]  1/(patch_norm) for the 2x64 positions
//   [34304, 35360) cs   : float[4][66] per-(row,col) sum_c x^2 (padded)
//   [35360, 43552) csp  : float[4][8][64] staging partials for cs
//   pool (epilogue only) aliases [0, 32768): float[256][32]
// ---------------------------------------------------------------------------
__global__ __launch_bounds__(512, 4) void ckn_main(
    const float* __restrict__ x,
    const ushort* __restrict__ wt,
    float* __restrict__ out) {
  __shared__ __align__(16) char smem[43552];
  char*  const xs   = smem;
  float* const invp = (float*)(smem + 33792);
  float* const cs   = (float*)(smem + 34304);
  float* const csp  = (float*)(smem + 35360);
  float* const pool = (float*)smem;

  const int tid = threadIdx.x;
  const int y0  = blockIdx.x;  // output row (pooled), image rows 2y0..2y0+1
  const int b   = blockIdx.y;  // image

  // ---- zero the pad columns (col 0 and 65, all 4 rows) ----
  if (tid < 64) {
    const int r4 = tid >> 4, colsel = (tid >> 3) & 1, cblk = tid & 7;
    const int col = colsel * 65;
    *(f32x4*)(xs + r4 * 8448 + col * 128 + cblk * 16) =
        (f32x4){0.f, 0.f, 0.f, 0.f};
  }

  // ---- stage 4 image rows (2y0-1 .. 2y0+2): fp32 -> bf16, swizzled ----
  {
    const int xx = tid & 63;
    const int cg = tid >> 6;                 // 0..7 (c block of 8)
    const int col = xx + 1;                  // physical col (pad at 0)
    const int sw = (cg * 16) ^ ((col & 7) << 4);
#pragma unroll
    for (int r4 = 0; r4 < 4; ++r4) {
      const int y_img = 2 * y0 - 1 + r4;
      char* dst = xs + r4 * 8448 + col * 128 + sw;
      if ((unsigned)y_img < 64u) {
        const float* src =
            x + (((size_t)b * 64 + cg * 8) * 64 + y_img) * 64 + xx;
        float ss = 0.f;
        union { bf16x8 v; ushort u[8]; } pk;
#pragma unroll
        for (int j = 0; j < 8; ++j) {
          const float f = src[(size_t)j * 4096];
          ss += f * f;
          __hip_bfloat16 h = __float2bfloat16(f);
          pk.u[j] = *reinterpret_cast<ushort*>(&h);
        }
        *(bf16x8*)dst = pk.v;
        csp[(r4 * 8 + cg) * 64 + xx] = ss;
      } else {
        *(bf16x8*)dst = (bf16x8){0, 0, 0, 0, 0, 0, 0, 0};
        csp[(r4 * 8 + cg) * 64 + xx] = 0.f;
      }
    }
  }
  __syncthreads();

  // ---- reduce csp -> cs (+ zero cs pad cols) ----
  if (tid < 256) {
    const int r4 = tid >> 6, xc = tid & 63;
    float s = 0.f;
#pragma unroll
    for (int cg = 0; cg < 8; ++cg) s += csp[(r4 * 8 + cg) * 64 + xc];
    cs[r4 * 66 + xc + 1] = s;
  }
  if (tid >= 256 && tid < 264) {
    const int t = tid - 256;
    cs[(t >> 1) * 66 + (t & 1) * 65] = 0.f;
  }
  __syncthreads();

  // ---- patch norms: invp[ry*64+xx] = 1/(sqrt(sum 3x3 cs)+1e-8) ----
  if (tid < 128) {
    const int ry = tid >> 6, xp = tid & 63;
    float s = 0.f;
#pragma unroll
    for (int dr = 0; dr < 3; ++dr)
#pragma unroll
      for (int dc = 0; dc < 3; ++dc) s += cs[(ry + dr) * 66 + xp + dc];
    invp[tid] = 1.0f / (sqrtf(fmaxf(s, 0.f)) + 1e-8f);
  }
  __syncthreads();

  // ---- K-loop GEMM: 8 waves = 2(M) x 4(N), wave tile 64x64 ----
  const int lane   = tid & 63;
  const int wid    = tid >> 6;
  const int wave_m = wid & 1;   // output row within pair
  const int wave_n = wid >> 1;  // 64-wide N chunk
  const int lane16 = lane & 15;
  const int klane  = lane >> 4;
  const int o_base = wave_n * 64;

  f32x4 acc[4][4];
#pragma unroll
  for (int i = 0; i < 4; ++i)
#pragma unroll
    for (int j = 0; j < 4; ++j) acc[i][j] = (f32x4){0.f, 0.f, 0.f, 0.f};

  const ushort* wbase = wt + (o_base + lane16) * 576 + klane * 8;

#pragma unroll
  for (int ks = 0; ks < 18; ++ks) {
    const int t9 = ks >> 1;
    const int kh = t9 / 3, kw = t9 % 3;
    const int cb = (ks & 1) * 64 + klane * 16;  // byte offset of c-block
    bf16x8 bfrag[4];
#pragma unroll
    for (int fn = 0; fn < 4; ++fn)
      bfrag[fn] = *(const bf16x8*)(wbase + fn * 16 * 576 + ks * 32);
    const int r4 = wave_m + kh;
#pragma unroll
    for (int fm = 0; fm < 4; ++fm) {
      const int col = fm * 16 + lane16 + kw;
      const int addr = r4 * 8448 + col * 128 + (cb ^ ((col & 7) << 4));
      const bf16x8 afrag = *(const bf16x8*)(xs + addr);
#pragma unroll
      for (int fn = 0; fn < 4; ++fn)
        acc[fm][fn] = __builtin_amdgcn_mfma_f32_16x16x32_bf16(
            afrag, bfrag[fn], acc[fm][fn], 0, 0, 0);
    }
  }

  // ---- epilogue: exp(cos-1) then x-pool in-register ----
  float ep0[4][4], ep1[4][4];
#pragma unroll
  for (int fm = 0; fm < 4; ++fm) {
    const int m = wave_m * 64 + fm * 16 + klane * 4;
    const f32x4 ip = *(const f32x4*)(invp + m);
#pragma unroll
    for (int fn = 0; fn < 4; ++fn) {
      const f32x4 v = acc[fm][fn];
      const float e0 = __expf(v[0] * ip[0] - 1.f);
      const float e1 = __expf(v[1] * ip[1] - 1.f);
      const float e2 = __expf(v[2] * ip[2] - 1.f);
      const float e3 = __expf(v[3] * ip[3] - 1.f);
      ep0[fm][fn] = e0 + e1;   // x-pair (2ox, 2ox+1)
      ep1[fm][fn] = e2 + e3;   // x-pair (2ox+2, 2ox+3)
    }
  }
  __syncthreads();  // all xs reads done; pool may alias xs now

  if (wave_m == 1) {
#pragma unroll
    for (int fm = 0; fm < 4; ++fm) {
      const int ox = fm * 8 + klane * 2;
#pragma unroll
      for (int fn = 0; fn < 4; ++fn) {
        const int o = o_base + fn * 16 + lane16;
        *(float2*)(pool + o * 32 + ox) = make_float2(ep0[fm][fn], ep1[fm][fn]);
      }
    }
  }
  __syncthreads();

  if (wave_m == 0) {
#pragma unroll
    for (int fm = 0; fm < 4; ++fm) {
      const int ox = fm * 8 + klane * 2;
#pragma unroll
      for (int fn = 0; fn < 4; ++fn) {
        const int o = o_base + fn * 16 + lane16;
        const float2 othr = *(const float2*)(pool + o * 32 + ox);
        const float r0 = 0.25f * (ep0[fm][fn] + othr.x);
        const float r1 = 0.25f * (ep1[fm][fn] + othr.y);
        *(float2*)(out + ((((size_t)b * 256 + o) * 32 + y0) * 32 + ox)) =
            make_float2(r0, r1);
      }
    }
  }
}

// ---------------------------------------------------------------------------
extern "C" void kernel_launch(void* const* d_in, const int* in_sizes, int n_in,
                              void* d_out, int out_size, void* d_ws,
                              size_t ws_size, hipStream_t stream) {
  const float* x = (const float*)d_in[0];
  const float* w = (const float*)d_in[1];
  float* out = (float*)d_out;
  ushort* wt = (ushort*)d_ws;  // 256*576*2 = 294912 bytes of scratch

  wnorm_kernel<<<dim3(256), dim3(64), 0, stream>>>(w, wt);
  ckn_main<<<dim3(32, 32), dim3(512), 0, stream>>>(x, wt, out);
}